// Round 6
// baseline (4847.414 us; speedup 1.0000x reference)
//
#include <hip/hip_runtime.h>
#include <hip/hip_cooperative_groups.h>
#include <math.h>

// ---------------------------------------------------------------------------
// JTNN decoder forward on MI355X.  v6: cooperative single-launch GRU scan.
//  * k_scan: 256 blocks x 1024 threads (1 block/CU, 16 waves = 4/SIMD),
//    loop t=0..31 with grid.sync(); Ur B-frags + biases register-resident
//    across all steps; Wr/Wz/Wh refetched per step (L2, coalesced);
//    __threadfence() before grid.sync for cross-XCD hbuf visibility.
//  * k_heads: merged pred+stop (unchanged from v5).
//  * MFMA layouts (validated R2-R5): A[m=lane&15][k=32*kb+8*q+j],
//    B[k][n=lane&15], D[row=4*q+i][col=lane&15].
// ---------------------------------------------------------------------------

namespace cg = cooperative_groups;

namespace {

constexpr int T_  = 32;
constexpr int N_  = 1024;
constexpr int H_  = 256;
constexpr int NB_ = 15;
constexpr int E_  = T_ * N_;      // 32768
constexpr int B_  = 256;
constexpr int PREDB_ = (B_ + E_) / 64;   // 516
constexpr int STOPB_ = (E_ + B_) / 64;   // 516

typedef unsigned short u16;
typedef unsigned int  uix4  __attribute__((ext_vector_type(4)));
typedef __bf16        bf16x8 __attribute__((ext_vector_type(8)));
typedef float         f32x4  __attribute__((ext_vector_type(4)));

__device__ __forceinline__ float sig_(float x){ return 1.f / (1.f + __expf(-x)); }

__device__ __forceinline__ float b2f(u16 u){
  union { unsigned int i; float f; } v; v.i = ((unsigned int)u) << 16; return v.f;
}
__device__ __forceinline__ u16 f2b(float f){
  union { float f; unsigned int i; } v; v.f = f;
  const unsigned int r = v.i + 0x7fffu + ((v.i >> 16) & 1u);
  return (u16)(r >> 16);
}
__device__ __forceinline__ f32x4 mfma16(uix4 a, uix4 b, f32x4 c){
  return __builtin_amdgcn_mfma_f32_16x16x32_bf16(
      __builtin_bit_cast(bf16x8, a), __builtin_bit_cast(bf16x8, b), c, 0, 0, 0);
}

// ---- fp32 -> bf16 conversion (once per launch) ----------------------------
__global__ __launch_bounds__(256) void k_cvt(
    const float* __restrict__ emb, const float* __restrict__ xt,
    const float* __restrict__ Ww,  const float* __restrict__ Wo,
    const float* __restrict__ Ui,  const float* __restrict__ Uw,
    const float* __restrict__ Wz,  const float* __restrict__ Wr,
    const float* __restrict__ Ur,  const float* __restrict__ Wh,
    u16* __restrict__ o_emb, u16* __restrict__ o_xt, u16* __restrict__ o_Ww,
    u16* __restrict__ o_Wo,  u16* __restrict__ o_Ui, u16* __restrict__ o_Uw,
    u16* __restrict__ o_Wz,  u16* __restrict__ o_Wr, u16* __restrict__ o_Ur,
    u16* __restrict__ o_Wh)
{
  int i = blockIdx.x * 256 + threadIdx.x;
  if (i < 204800){ o_emb[i] = f2b(emb[i]); return; }  i -= 204800;
  if (i <  32768){ o_xt[i]  = f2b(xt[i]);  return; }  i -=  32768;
  if (i <  98304){ o_Ww[i]  = f2b(Ww[i]);  return; }  i -=  98304;
  if (i < 204800){ o_Wo[i]  = f2b(Wo[i]);  return; }  i -= 204800;
  if (i < 131072){ o_Ui[i]  = f2b(Ui[i]);  return; }  i -= 131072;
  if (i <  98304){ o_Uw[i]  = f2b(Uw[i]);  return; }  i -=  98304;
  if (i < 131072){ o_Wz[i]  = f2b(Wz[i]);  return; }  i -= 131072;
  if (i <  65536){ o_Wr[i]  = f2b(Wr[i]);  return; }  i -=  65536;
  if (i <  65536){ o_Ur[i]  = f2b(Ur[i]);  return; }  i -=  65536;
  if (i < 131072){ o_Wh[i]  = f2b(Wh[i]); }
}

// ---- init ------------------------------------------------------------------
__global__ __launch_bounds__(256) void k_init(float* __restrict__ acc,
                                              u16* __restrict__ hb16){
  const int tid = threadIdx.x;
  if (tid < 16) acc[tid] = 0.f;
  hb16[(size_t)E_ * H_ + tid] = 0;   // row E = zero pad slot
}

// ---- cooperative GRU scan: all 32 steps in one launch ---------------------
// 256 blocks x 1024 threads; block = 4 msg rows/step; wave = 16-col slice.
// (row,nb) pairs packed 16/A-tile, pair = nb*4 + row -> D row 4q+i maps to
// (msg row=i, nb=4j+q); nb=15 pad = hbuf row E (zeros).
__global__ __launch_bounds__(1024, 4) void k_scan(
    const u16* __restrict__ emb16,
    const u16* __restrict__ Wz16, const float* __restrict__ Wzb,
    const u16* __restrict__ Wr16, const float* __restrict__ Wrb,
    const u16* __restrict__ Ur16,
    const u16* __restrict__ Wh16, const float* __restrict__ Whb,
    const int* __restrict__ word_ids, const int* __restrict__ h_nei,
    u16* __restrict__ hb16)
{
  __shared__ __align__(16) u16 hn[64 * 264];   // 64 (row,nb) pairs, padded
  __shared__ __align__(16) u16 xs[4][264];     // embedding rows
  __shared__ __align__(16) u16 sh[4][264];     // sum_h (A-layout)
  __shared__ __align__(16) u16 gl[4][264];     // gated (A-layout)
  __shared__ int s_wid[4];
  __shared__ int s_hidx[64];                   // pair p = nb*4 + row

  const int tid = threadIdx.x;
  const int w = tid >> 6, ln = tid & 63, q = ln >> 4, m = ln & 15;
  const int col = w * 16 + m;                  // this wave-lane's output col

  // scan-persistent state: Ur B-frags (hot inner GEMM) + biases
  uix4 Bur[8];
  {
    const u16* bp = Ur16 + (size_t)col * 256 + q * 8;
    #pragma unroll
    for (int kb = 0; kb < 8; ++kb) Bur[kb] = *(const uix4*)(bp + kb*32);
  }
  const float wrb = Wrb[col], wzb = Wzb[col], whb = Whb[col];

  cg::grid_group grid = cg::this_grid();

  for (int t = 0; t < T_; ++t){
    const int base = t * N_ + blockIdx.x * 4;  // first message row this step

    if (tid < 4) s_wid[tid] = word_ids[base + tid];
    if (tid < 64){
      const int row = tid & 3, nb = tid >> 2;
      s_hidx[tid] = (nb < NB_) ? h_nei[(base + row) * NB_ + nb] : E_;
    }
    __syncthreads();

    // stage 64 pair-rows (512B coalesced each) + 4 embedding rows
    #pragma unroll
    for (int it = 0; it < 2; ++it){
      const int task = it * 1024 + tid;
      const int row = task >> 5, ch = task & 31;
      *(uix4*)(&hn[row*264 + ch*8]) =
          *(const uix4*)(hb16 + (size_t)s_hidx[row]*256 + ch*8);
    }
    if (tid < 128){
      const int row = tid >> 5, ch = tid & 31;
      *(uix4*)(&xs[row][ch*8]) =
          *(const uix4*)(emb16 + (size_t)s_wid[row]*256 + ch*8);
    }
    __syncthreads();

    // A-frag of x (rows replicated m&3)
    uix4 Ax[8];
    #pragma unroll
    for (int kb = 0; kb < 8; ++kb) Ax[kb] = *(const uix4*)(&xs[m & 3][kb*32 + q*8]);

    // xr = x @ Wr^T + b_r  (C-init tile; D row 4q+i == message i)
    f32x4 xr = {0.f, 0.f, 0.f, 0.f};
    {
      const u16* bp = Wr16 + (size_t)col * 256 + q * 8;
      #pragma unroll
      for (int kb = 0; kb < 8; ++kb) xr = mfma16(Ax[kb], *(const uix4*)(bp + kb*32), xr);
      #pragma unroll
      for (int i = 0; i < 4; ++i) xr[i] += wrb;
    }

    // r-gate GEMM over 4 pair-tiles (Bur register-resident)
    float ga[4] = {0.f,0.f,0.f,0.f}, su[4] = {0.f,0.f,0.f,0.f};
    #pragma unroll
    for (int j = 0; j < 4; ++j){
      uix4 Ah[8];
      #pragma unroll
      for (int kb = 0; kb < 8; ++kb)
        Ah[kb] = *(const uix4*)(&hn[(j*16 + m)*264 + kb*32 + q*8]);
      f32x4 a = xr;
      #pragma unroll
      for (int kb = 0; kb < 8; ++kb) a = mfma16(Ah[kb], Bur[kb], a);
      #pragma unroll
      for (int i = 0; i < 4; ++i){
        const float hv = b2f(hn[(j*16 + 4*q + i)*264 + col]);
        ga[i] += sig_(a[i]) * hv;
        su[i] += hv;
      }
    }

    // reduce over nb partition (quads): nb = 4j+q -> sum over q
    #pragma unroll
    for (int i = 0; i < 4; ++i){
      ga[i] += __shfl_xor(ga[i], 16, 64);
      ga[i] += __shfl_xor(ga[i], 32, 64);
      su[i] += __shfl_xor(su[i], 16, 64);
      su[i] += __shfl_xor(su[i], 32, 64);
    }
    if (q == 0){
      #pragma unroll
      for (int i = 0; i < 4; ++i){
        sh[i][col] = f2b(su[i]);
        gl[i][col] = f2b(ga[i]);
      }
    }
    __syncthreads();

    // z / h~ GEMMs (K=512), combine, store (q==0 lanes own real rows 0..3)
    f32x4 az = {0.f,0.f,0.f,0.f}, ah = {0.f,0.f,0.f,0.f};
    {
      uix4 As[8];
      #pragma unroll
      for (int kb = 0; kb < 8; ++kb) As[kb] = *(const uix4*)(&sh[m & 3][kb*32 + q*8]);
      const u16* bz = Wz16 + (size_t)col * 512 + q * 8;
      #pragma unroll
      for (int kb = 0; kb < 8; ++kb) az = mfma16(Ax[kb], *(const uix4*)(bz + kb*32), az);
      #pragma unroll
      for (int kb = 0; kb < 8; ++kb) az = mfma16(As[kb], *(const uix4*)(bz + 256 + kb*32), az);
    }
    {
      uix4 Ag[8];
      #pragma unroll
      for (int kb = 0; kb < 8; ++kb) Ag[kb] = *(const uix4*)(&gl[m & 3][kb*32 + q*8]);
      const u16* bh = Wh16 + (size_t)col * 512 + q * 8;
      #pragma unroll
      for (int kb = 0; kb < 8; ++kb) ah = mfma16(Ax[kb], *(const uix4*)(bh + kb*32), ah);
      #pragma unroll
      for (int kb = 0; kb < 8; ++kb) ah = mfma16(Ag[kb], *(const uix4*)(bh + 256 + kb*32), ah);
    }
    if (q == 0){
      #pragma unroll
      for (int i = 0; i < 4; ++i){
        const float z  = sig_(az[i] + wzb);
        const float ht = tanhf(ah[i] + whb);
        const float nh = (1.f - z) * su[i] + z * ht;
        hb16[(size_t)(base + i) * 256 + col] = f2b(nh);
      }
    }

    __threadfence();        // make new_h visible across XCDs
    grid.sync();            // step barrier
  }
}

// ---- merged heads ----------------------------------------------------------
struct PredSm {
  u16   hd[4][16][264];
  int   tgt[64];
  float mask[64];
  float nll[64], hit[64], msk[64];
};
struct StopSm {
  u16   so[64][264];
  int   oidx[64][NB_];
  int   wid[64], ctx[64];
  float tgt[64];
  float b0[64], b1[64];
};
constexpr size_t SMU_ = sizeof(StopSm) > sizeof(PredSm) ? sizeof(StopSm)
                                                        : sizeof(PredSm);

__device__ void pred_body(int bid, char* smraw,
    const u16* __restrict__ hb16, const u16* __restrict__ Ww16,
    const float* __restrict__ Wb, const u16* __restrict__ Wo16,
    const float* __restrict__ Wob, const u16* __restrict__ xt16,
    const int* __restrict__ contexts, const int* __restrict__ pred_targets,
    const int* __restrict__ direction, const int* __restrict__ root_word_ids,
    float* __restrict__ accum)
{
  PredSm& sm = *(PredSm*)smraw;
  const int tid = threadIdx.x;
  const int p0  = bid * 64;
  const int w = tid >> 6, ln = tid & 63, q = ln >> 4, m = ln & 15;
  const int r0 = w * 16;

  if (tid < 64){
    const int p = p0 + tid;
    int tg; float mk;
    if (p < B_){ tg = root_word_ids[p]; mk = 1.f; }
    else { tg = pred_targets[p - B_]; mk = (float)direction[p - B_]; }
    sm.tgt[tid] = tg; sm.mask[tid] = mk;
  }
  const int p    = p0 + r0 + m;
  const int hrow = (p < B_) ? E_ : (p - B_);
  const int ctx  = (p < B_) ? p  : contexts[p - B_];
  __syncthreads();

  // GEMM1: hid = relu([h | xtree] @ Ww^T + Wb)   (K = 384)
  uix4 A1[12];
  {
    const u16* hp = hb16 + (size_t)hrow * 256 + q * 8;
    #pragma unroll
    for (int j = 0; j < 8; ++j) A1[j] = *(const uix4*)(hp + j * 32);
    const u16* xp = xt16 + (size_t)ctx * 128 + q * 8;
    #pragma unroll
    for (int j = 0; j < 4; ++j) A1[8 + j] = *(const uix4*)(xp + j * 32);
  }
  for (int t = 0; t < 16; ++t){
    f32x4 acc = {0.f, 0.f, 0.f, 0.f};
    const u16* bp = Ww16 + (size_t)(t*16 + m) * 384 + q * 8;
    #pragma unroll
    for (int j = 0; j < 12; ++j) acc = mfma16(A1[j], *(const uix4*)(bp + j*32), acc);
    const float bias = Wb[t*16 + m];
    #pragma unroll
    for (int i = 0; i < 4; ++i)
      sm.hd[w][q*4 + i][t*16 + m] = f2b(fmaxf(acc[i] + bias, 0.f));
  }
  __syncthreads();

  // GEMM2: scores = hid @ Wo^T + Wob, online softmax, B-prefetch
  uix4 A2[8];
  #pragma unroll
  for (int j = 0; j < 8; ++j) A2[j] = *(const uix4*)(&sm.hd[w][m][j*32 + q*8]);

  int tgtc[4];
  #pragma unroll
  for (int i = 0; i < 4; ++i) tgtc[i] = sm.tgt[r0 + q*4 + i];
  float mrun[4], lrun[4], amax[4], tval[4]; int aidx[4];
  #pragma unroll
  for (int i = 0; i < 4; ++i){
    mrun[i] = -1e30f; lrun[i] = 0.f; amax[i] = -1e30f; tval[i] = -1e30f; aidx[i] = 0;
  }

  uix4 Bf[8];
  {
    const u16* bp = Wo16 + (size_t)m * 256 + q * 8;
    #pragma unroll
    for (int j = 0; j < 8; ++j) Bf[j] = *(const uix4*)(bp + j*32);
  }
  for (int t = 0; t < 50; ++t){
    uix4 Bn[8];
    if (t < 49){
      const u16* bp = Wo16 + (size_t)((t+1)*16 + m) * 256 + q * 8;
      #pragma unroll
      for (int j = 0; j < 8; ++j) Bn[j] = *(const uix4*)(bp + j*32);
    } else {
      #pragma unroll
      for (int j = 0; j < 8; ++j) Bn[j] = Bf[j];
    }
    f32x4 acc = {0.f, 0.f, 0.f, 0.f};
    #pragma unroll
    for (int j = 0; j < 8; ++j) acc = mfma16(A2[j], Bf[j], acc);
    const int c = t*16 + m;
    const float bias = Wob[c];
    #pragma unroll
    for (int i = 0; i < 4; ++i){
      const float v = acc[i] + bias;
      if (c == tgtc[i]) tval[i] = v;
      if (v > amax[i]){ amax[i] = v; aidx[i] = c; }
      const float nm = fmaxf(mrun[i], v);
      lrun[i] = lrun[i] * __expf(mrun[i] - nm) + __expf(v - nm);
      mrun[i] = nm;
    }
    #pragma unroll
    for (int j = 0; j < 8; ++j) Bf[j] = Bn[j];
  }
  #pragma unroll
  for (int msk = 1; msk < 16; msk <<= 1){
    #pragma unroll
    for (int i = 0; i < 4; ++i){
      const float om = __shfl_xor(mrun[i], msk, 64);
      const float ol = __shfl_xor(lrun[i], msk, 64);
      const float nm = fmaxf(mrun[i], om);
      lrun[i] = lrun[i] * __expf(mrun[i] - nm) + ol * __expf(om - nm);
      mrun[i] = nm;
      const float oa = __shfl_xor(amax[i], msk, 64);
      const int   oi = __shfl_xor(aidx[i], msk, 64);
      if (oa > amax[i] || (oa == amax[i] && oi < aidx[i])){ amax[i] = oa; aidx[i] = oi; }
      tval[i] = fmaxf(tval[i], __shfl_xor(tval[i], msk, 64));
    }
  }
  if (m == 0){
    #pragma unroll
    for (int i = 0; i < 4; ++i){
      const int r = r0 + q*4 + i;
      const float mk  = sm.mask[r];
      const float nll = mrun[i] + __logf(lrun[i]) - tval[i];
      sm.nll[r] = nll * mk;
      sm.hit[r] = (aidx[i] == tgtc[i]) ? mk : 0.f;
      sm.msk[r] = mk;
    }
  }
  __syncthreads();
  if (tid < 64){
    float a = sm.nll[tid], b = sm.hit[tid], c2 = sm.msk[tid];
    #pragma unroll
    for (int off = 32; off > 0; off >>= 1){
      a += __shfl_down(a, off, 64); b += __shfl_down(b, off, 64); c2 += __shfl_down(c2, off, 64);
    }
    if (tid == 0){
      atomicAdd(&accum[0], a); atomicAdd(&accum[1], b); atomicAdd(&accum[2], c2);
    }
  }
}

__device__ void stop_body(int bid, char* smraw,
    const u16* __restrict__ hb16, const u16* __restrict__ emb16,
    const u16* __restrict__ Ui16, const float* __restrict__ Uib,
    const u16* __restrict__ Uw16, const float* __restrict__ Ub,
    const float* __restrict__ Uo, const float* __restrict__ Uob,
    const u16* __restrict__ xt16,
    const int* __restrict__ word_ids, const int* __restrict__ o_nei,
    const int* __restrict__ contexts, const int* __restrict__ direction,
    const int* __restrict__ root_word_ids, const int* __restrict__ root_o_idx,
    float* __restrict__ accum)
{
  StopSm& sm = *(StopSm*)smraw;
  const int tid = threadIdx.x;
  const int p0  = bid * 64;
  const int w = tid >> 6, ln = tid & 63, q = ln >> 4, m = ln & 15;
  const int r0 = w * 16;

  if (tid < 64){
    const int s = p0 + tid;
    if (s < E_){ sm.wid[tid] = word_ids[s]; sm.ctx[tid] = contexts[s];
                 sm.tgt[tid] = (float)direction[s]; }
    else { const int b = s - E_; sm.wid[tid] = root_word_ids[b]; sm.ctx[tid] = b;
           sm.tgt[tid] = 0.f; }
  }
  for (int k = tid; k < 64 * NB_; k += 256){
    const int r = k / NB_, nb = k % NB_;
    const int s = p0 + r;
    sm.oidx[r][nb] = (s < E_) ? o_nei[(size_t)s * NB_ + nb]
                              : root_o_idx[(size_t)(s - E_) * NB_ + nb];
  }
  __syncthreads();

  // stage sum_o: task-parallel (row, 16-col slice), coalesced uix4 gathers
  for (int it = 0; it < 4; ++it){
    const int task = it * 256 + tid;
    const int row = task >> 4, sl = task & 15;
    float a[16];
    #pragma unroll
    for (int c = 0; c < 16; ++c) a[c] = 0.f;
    #pragma unroll
    for (int nb = 0; nb < NB_; ++nb){
      const u16* p = hb16 + (size_t)sm.oidx[row][nb] * 256 + sl * 16;
      const uix4 v0 = *(const uix4*)(p);
      const uix4 v1 = *(const uix4*)(p + 8);
      #pragma unroll
      for (int c = 0; c < 4; ++c){
        a[2*c]     += b2f((u16)(v0[c] & 0xffffu));
        a[2*c + 1] += b2f((u16)(v0[c] >> 16));
        a[8 + 2*c] += b2f((u16)(v1[c] & 0xffffu));
        a[9 + 2*c] += b2f((u16)(v1[c] >> 16));
      }
    }
    uix4 o0, o1;
    #pragma unroll
    for (int c = 0; c < 4; ++c){
      o0[c] = (unsigned)f2b(a[2*c])   | ((unsigned)f2b(a[2*c+1]) << 16);
      o1[c] = (unsigned)f2b(a[8+2*c]) | ((unsigned)f2b(a[9+2*c]) << 16);
    }
    *(uix4*)(&sm.so[row][sl*16])     = o0;
    *(uix4*)(&sm.so[row][sl*16 + 8]) = o1;
  }
  __syncthreads();

  // A for GEMM1: [emb | sum_o]  (K = 512)
  uix4 A1[16];
  {
    const u16* ep = emb16 + (size_t)sm.wid[r0 + m] * 256 + q * 8;
    #pragma unroll
    for (int j = 0; j < 8; ++j) A1[j] = *(const uix4*)(ep + j * 32);
    #pragma unroll
    for (int j = 0; j < 8; ++j) A1[8 + j] = *(const uix4*)(&sm.so[r0 + m][j*32 + q*8]);
  }
  __syncthreads();   // all waves captured so -> safe to overwrite with h1

  // GEMM1: h1 = relu(inp @ Ui^T + Uib) -> so region (wave-private rows)
  for (int t = 0; t < 16; ++t){
    f32x4 acc = {0.f, 0.f, 0.f, 0.f};
    const u16* bp = Ui16 + (size_t)(t*16 + m) * 512 + q * 8;
    #pragma unroll
    for (int j = 0; j < 16; ++j) acc = mfma16(A1[j], *(const uix4*)(bp + j*32), acc);
    const float bias = Uib[t*16 + m];
    #pragma unroll
    for (int i = 0; i < 4; ++i)
      sm.so[r0 + q*4 + i][t*16 + m] = f2b(fmaxf(acc[i] + bias, 0.f));
  }
  __syncthreads();

  // GEMM2: h2 = relu([h1 | xtree] @ Uw^T + Ub); s = h2 . Uo + Uob
  uix4 A2[12];
  {
    #pragma unroll
    for (int j = 0; j < 8; ++j) A2[j] = *(const uix4*)(&sm.so[r0 + m][j*32 + q*8]);
    const u16* xp = xt16 + (size_t)sm.ctx[r0 + m] * 128 + q * 8;
    #pragma unroll
    for (int j = 0; j < 4; ++j) A2[8 + j] = *(const uix4*)(xp + j * 32);
  }
  float sp[4] = {0.f, 0.f, 0.f, 0.f};
  uix4 Bf[12];
  {
    const u16* bp = Uw16 + (size_t)m * 384 + q * 8;
    #pragma unroll
    for (int j = 0; j < 12; ++j) Bf[j] = *(const uix4*)(bp + j*32);
  }
  for (int t = 0; t < 16; ++t){
    uix4 Bn[12];
    if (t < 15){
      const u16* bp = Uw16 + (size_t)((t+1)*16 + m) * 384 + q * 8;
      #pragma unroll
      for (int j = 0; j < 12; ++j) Bn[j] = *(const uix4*)(bp + j*32);
    } else {
      #pragma unroll
      for (int j = 0; j < 12; ++j) Bn[j] = Bf[j];
    }
    f32x4 acc = {0.f, 0.f, 0.f, 0.f};
    #pragma unroll
    for (int j = 0; j < 12; ++j) acc = mfma16(A2[j], Bf[j], acc);
    const int c = t*16 + m;
    const float bias = Ub[c];
    const float uo   = Uo[c];
    #pragma unroll
    for (int i = 0; i < 4; ++i) sp[i] += fmaxf(acc[i] + bias, 0.f) * uo;
    #pragma unroll
    for (int j = 0; j < 12; ++j) Bf[j] = Bn[j];
  }
  #pragma unroll
  for (int msk = 1; msk < 16; msk <<= 1){
    #pragma unroll
    for (int i = 0; i < 4; ++i) sp[i] += __shfl_xor(sp[i], msk, 64);
  }
  if (m == 0){
    const float ub = Uob[0];
    #pragma unroll
    for (int i = 0; i < 4; ++i){
      const int r = r0 + q*4 + i;
      const float s   = sp[i] + ub;
      const float tgt = sm.tgt[r];
      sm.b0[r] = fmaxf(s, 0.f) - s * tgt + log1pf(__expf(-fabsf(s)));
      const float pb = (s >= 0.f) ? 1.f : 0.f;
      sm.b1[r] = (pb == tgt) ? 1.f : 0.f;
    }
  }
  __syncthreads();
  if (tid < 64){
    float a = sm.b0[tid], b = sm.b1[tid];
    #pragma unroll
    for (int off = 32; off > 0; off >>= 1){
      a += __shfl_down(a, off, 64); b += __shfl_down(b, off, 64);
    }
    if (tid == 0){ atomicAdd(&accum[3], a); atomicAdd(&accum[4], b); }
  }
}

__global__ __launch_bounds__(256) void k_heads(
    const u16* __restrict__ hb16, const u16* __restrict__ emb16,
    const u16* __restrict__ Ww16, const float* __restrict__ Wb,
    const u16* __restrict__ Wo16, const float* __restrict__ Wob,
    const u16* __restrict__ Ui16, const float* __restrict__ Uib,
    const u16* __restrict__ Uw16, const float* __restrict__ Ub,
    const float* __restrict__ Uo, const float* __restrict__ Uob,
    const u16* __restrict__ xt16,
    const int* __restrict__ word_ids, const int* __restrict__ o_nei,
    const int* __restrict__ contexts, const int* __restrict__ pred_targets,
    const int* __restrict__ direction, const int* __restrict__ root_word_ids,
    const int* __restrict__ root_o_idx, float* __restrict__ accum)
{
  __shared__ __align__(16) char smraw[SMU_];
  const int b = blockIdx.x;
  if (b < PREDB_){
    pred_body(b, smraw, hb16, Ww16, Wb, Wo16, Wob, xt16,
              contexts, pred_targets, direction, root_word_ids, accum);
  } else {
    stop_body(b - PREDB_, smraw, hb16, emb16, Ui16, Uib, Uw16, Ub, Uo, Uob,
              xt16, word_ids, o_nei, contexts, direction,
              root_word_ids, root_o_idx, accum);
  }
}

// ---- finalize --------------------------------------------------------------
__global__ void k_final(const float* __restrict__ acc, float* __restrict__ out){
  if (threadIdx.x == 0 && blockIdx.x == 0){
    out[0] = acc[0] / (float)B_;               // pred_loss
    out[1] = acc[3] / (float)B_;               // stop_loss
    out[2] = acc[1] / acc[2];                  // pred_acc
    out[3] = acc[4] / (float)(E_ + B_);        // stop_acc
  }
}

} // anonymous namespace

extern "C" void kernel_launch(void* const* d_in, const int* in_sizes, int n_in,
                              void* d_out, int out_size, void* d_ws, size_t ws_size,
                              hipStream_t stream)
{
  const float* emb   = (const float*)d_in[0];
  const float* Wz    = (const float*)d_in[1];
  const float* Wzb   = (const float*)d_in[2];
  const float* Wr    = (const float*)d_in[3];
  const float* Wrb   = (const float*)d_in[4];
  const float* Ur    = (const float*)d_in[5];
  const float* Wh    = (const float*)d_in[6];
  const float* Whb   = (const float*)d_in[7];
  const float* Ww    = (const float*)d_in[8];
  const float* Wb    = (const float*)d_in[9];
  const float* Wo    = (const float*)d_in[10];
  const float* Wob   = (const float*)d_in[11];
  const float* Uw    = (const float*)d_in[12];
  const float* Ub    = (const float*)d_in[13];
  const float* Ui    = (const float*)d_in[14];
  const float* Uib   = (const float*)d_in[15];
  const float* Uo    = (const float*)d_in[16];
  const float* Uob   = (const float*)d_in[17];
  const float* xtree = (const float*)d_in[18];
  const int* word_ids      = (const int*)d_in[19];
  const int* h_nei_idx     = (const int*)d_in[20];
  const int* o_nei_idx     = (const int*)d_in[21];
  const int* contexts      = (const int*)d_in[22];
  const int* pred_targets  = (const int*)d_in[23];
  const int* direction     = (const int*)d_in[24];
  const int* root_word_ids = (const int*)d_in[25];
  const int* root_o_idx    = (const int*)d_in[26];

  char*  wsb   = (char*)d_ws;
  float* accum = (float*)wsb;
  size_t off = 256;
  u16* hb16  = (u16*)(wsb + off); off += (size_t)(E_ + 1) * H_ * 2;  // 16.78 MB
  u16* emb16 = (u16*)(wsb + off); off += 204800u * 2;
  u16* xt16  = (u16*)(wsb + off); off += 32768u * 2;
  u16* Ww16  = (u16*)(wsb + off); off += 98304u * 2;
  u16* Wo16  = (u16*)(wsb + off); off += 204800u * 2;
  u16* Ui16  = (u16*)(wsb + off); off += 131072u * 2;
  u16* Uw16  = (u16*)(wsb + off); off += 98304u * 2;
  u16* Wz16  = (u16*)(wsb + off); off += 131072u * 2;
  u16* Wr16  = (u16*)(wsb + off); off += 65536u * 2;
  u16* Ur16  = (u16*)(wsb + off); off += 65536u * 2;
  u16* Wh16  = (u16*)(wsb + off); off += 131072u * 2;
  float* out = (float*)d_out;

  hipLaunchKernelGGL(k_cvt, dim3(4544), dim3(256), 0, stream,
                     emb, xtree, Ww, Wo, Ui, Uw, Wz, Wr, Ur, Wh,
                     emb16, xt16, Ww16, Wo16, Ui16, Uw16,
                     Wz16, Wr16, Ur16, Wh16);
  hipLaunchKernelGGL(k_init, dim3(1), dim3(256), 0, stream, accum, hb16);

  // cooperative single-launch GRU scan
  {
    void* args[] = {
      (void*)&emb16, (void*)&Wz16, (void*)&Wzb, (void*)&Wr16, (void*)&Wrb,
      (void*)&Ur16,  (void*)&Wh16, (void*)&Whb, (void*)&word_ids,
      (void*)&h_nei_idx, (void*)&hb16
    };
    hipLaunchCooperativeKernel((const void*)k_scan, dim3(256), dim3(1024),
                               args, 0, stream);
  }

  hipLaunchKernelGGL(k_heads, dim3(PREDB_ + STOPB_), dim3(256), 0, stream,
                     hb16, emb16, Ww16, Wb, Wo16, Wob, Ui16, Uib, Uw16, Ub,
                     Uo, Uob, xt16, word_ids, o_nei_idx, contexts,
                     pred_targets, direction, root_word_ids, root_o_idx,
                     accum);

  hipLaunchKernelGGL(k_final, dim3(1), dim3(1), 0, stream, accum, out);
}

// Round 7
// 992.784 us; speedup vs baseline: 4.8826x; 4.8826x over previous
//
#include <hip/hip_runtime.h>
#include <math.h>

// ---------------------------------------------------------------------------
// JTNN decoder forward on MI355X.  v7: v5 structure (per-step launches) +
// precomputed x-side gate tables.
//  * xr/xz/xh = emb @ {Wr, Wz[:, :H], Wh[:, :H]}^T + bias depend only on the
//    word id -> computed once into 800x256 fp32 tables (k_tab). Per scan step
//    this removes the Wr GEMM, halves K of the z/h GEMMs (512->256), and
//    removes embedding staging: per-block weight traffic 640KB -> 256KB.
//  * k_gru: 1024 threads (16 waves), wave = 16-col slice, 4 msg rows/block,
//    grid 256. (row,nb) pairs packed 16/A-tile, pair = nb*4+row -> D row
//    4q+i = (msg i, nb 4j+q); quad shfl_xor(16/32) reduces ga/su.
//  * k_heads: merged pred+stop (v5, unchanged).
//  * Cooperative scan (v6) REVERTED: per-step device-scope fences invalidate
//    L2 on every XCD every step -> 2.6GB refetch/launch, 140us/step.
//  * MFMA layouts (validated R2-R5): A[m=lane&15][k=32*kb+8*q+j],
//    B[k][n=lane&15], D[row=4*q+i][col=lane&15].
// ---------------------------------------------------------------------------

namespace {

constexpr int T_  = 32;
constexpr int N_  = 1024;
constexpr int H_  = 256;
constexpr int NB_ = 15;
constexpr int E_  = T_ * N_;      // 32768
constexpr int B_  = 256;
constexpr int PREDB_ = (B_ + E_) / 64;   // 516
constexpr int STOPB_ = (E_ + B_) / 64;   // 516

typedef unsigned short u16;
typedef unsigned int  uix4  __attribute__((ext_vector_type(4)));
typedef __bf16        bf16x8 __attribute__((ext_vector_type(8)));
typedef float         f32x4  __attribute__((ext_vector_type(4)));

__device__ __forceinline__ float sig_(float x){ return 1.f / (1.f + __expf(-x)); }

__device__ __forceinline__ float b2f(u16 u){
  union { unsigned int i; float f; } v; v.i = ((unsigned int)u) << 16; return v.f;
}
__device__ __forceinline__ u16 f2b(float f){
  union { float f; unsigned int i; } v; v.f = f;
  const unsigned int r = v.i + 0x7fffu + ((v.i >> 16) & 1u);
  return (u16)(r >> 16);
}
__device__ __forceinline__ f32x4 mfma16(uix4 a, uix4 b, f32x4 c){
  return __builtin_amdgcn_mfma_f32_16x16x32_bf16(
      __builtin_bit_cast(bf16x8, a), __builtin_bit_cast(bf16x8, b), c, 0, 0, 0);
}

// ---- fp32 -> bf16 conversion (once per launch) ----------------------------
__global__ __launch_bounds__(256) void k_cvt(
    const float* __restrict__ emb, const float* __restrict__ xt,
    const float* __restrict__ Ww,  const float* __restrict__ Wo,
    const float* __restrict__ Ui,  const float* __restrict__ Uw,
    const float* __restrict__ Wz,  const float* __restrict__ Wr,
    const float* __restrict__ Ur,  const float* __restrict__ Wh,
    u16* __restrict__ o_emb, u16* __restrict__ o_xt, u16* __restrict__ o_Ww,
    u16* __restrict__ o_Wo,  u16* __restrict__ o_Ui, u16* __restrict__ o_Uw,
    u16* __restrict__ o_Wz,  u16* __restrict__ o_Wr, u16* __restrict__ o_Ur,
    u16* __restrict__ o_Wh)
{
  int i = blockIdx.x * 256 + threadIdx.x;
  if (i < 204800){ o_emb[i] = f2b(emb[i]); return; }  i -= 204800;
  if (i <  32768){ o_xt[i]  = f2b(xt[i]);  return; }  i -=  32768;
  if (i <  98304){ o_Ww[i]  = f2b(Ww[i]);  return; }  i -=  98304;
  if (i < 204800){ o_Wo[i]  = f2b(Wo[i]);  return; }  i -= 204800;
  if (i < 131072){ o_Ui[i]  = f2b(Ui[i]);  return; }  i -= 131072;
  if (i <  98304){ o_Uw[i]  = f2b(Uw[i]);  return; }  i -=  98304;
  if (i < 131072){ o_Wz[i]  = f2b(Wz[i]);  return; }  i -= 131072;
  if (i <  65536){ o_Wr[i]  = f2b(Wr[i]);  return; }  i -=  65536;
  if (i <  65536){ o_Ur[i]  = f2b(Ur[i]);  return; }  i -=  65536;
  if (i < 131072){ o_Wh[i]  = f2b(Wh[i]); }
}

// ---- init ------------------------------------------------------------------
__global__ __launch_bounds__(256) void k_init(float* __restrict__ acc,
                                              u16* __restrict__ hb16){
  const int tid = threadIdx.x;
  if (tid < 16) acc[tid] = 0.f;
  hb16[(size_t)E_ * H_ + tid] = 0;   // row E = zero pad slot
}

// ---- precompute x-side gate tables: 800x256 fp32, bias folded -------------
// grid 50 blocks (16 word rows each), 256 threads = 4 waves (64 cols each).
__global__ __launch_bounds__(256) void k_tab(
    const u16* __restrict__ emb16,
    const u16* __restrict__ Wr16, const float* __restrict__ Wrb,
    const u16* __restrict__ Wz16, const float* __restrict__ Wzb,
    const u16* __restrict__ Wh16, const float* __restrict__ Whb,
    float* __restrict__ xrtab, float* __restrict__ xztab,
    float* __restrict__ xhtab)
{
  const int tid = threadIdx.x;
  const int w = tid >> 6, ln = tid & 63, q = ln >> 4, m = ln & 15;
  const int r0 = blockIdx.x * 16;

  uix4 Ae[8];
  {
    const u16* ep = emb16 + (size_t)(r0 + m) * 256 + q * 8;
    #pragma unroll
    for (int kb = 0; kb < 8; ++kb) Ae[kb] = *(const uix4*)(ep + kb * 32);
  }
  #pragma unroll
  for (int nt = 0; nt < 4; ++nt){
    const int col = w * 64 + nt * 16 + m;
    f32x4 ar = {0.f,0.f,0.f,0.f}, az = {0.f,0.f,0.f,0.f}, ah = {0.f,0.f,0.f,0.f};
    const u16* br = Wr16 + (size_t)col * 256 + q * 8;
    const u16* bz = Wz16 + (size_t)col * 512 + q * 8;   // x-part of Wz
    const u16* bh = Wh16 + (size_t)col * 512 + q * 8;   // x-part of Wh
    #pragma unroll
    for (int kb = 0; kb < 8; ++kb){
      ar = mfma16(Ae[kb], *(const uix4*)(br + kb*32), ar);
      az = mfma16(Ae[kb], *(const uix4*)(bz + kb*32), az);
      ah = mfma16(Ae[kb], *(const uix4*)(bh + kb*32), ah);
    }
    const float rb = Wrb[col], zb = Wzb[col], hb = Whb[col];
    #pragma unroll
    for (int i = 0; i < 4; ++i){
      const size_t o = (size_t)(r0 + 4*q + i) * 256 + col;
      xrtab[o] = ar[i] + rb;
      xztab[o] = az[i] + zb;
      xhtab[o] = ah[i] + hb;
    }
  }
}

// ---- one GRU scan step: 1024 threads, 16 waves, wave = 16-col slice -------
__global__ __launch_bounds__(1024, 4) void k_gru(
    const u16* __restrict__ Wz16, const u16* __restrict__ Ur16,
    const u16* __restrict__ Wh16,
    const float* __restrict__ xrtab, const float* __restrict__ xztab,
    const float* __restrict__ xhtab,
    const int* __restrict__ word_ids, const int* __restrict__ h_nei,
    u16* __restrict__ hb16, int t)
{
  __shared__ __align__(16) u16 hn[64 * 264];   // 64 (row,nb) pairs, padded
  __shared__ __align__(16) u16 sh[4][264];     // sum_h (A-layout)
  __shared__ __align__(16) u16 gl[4][264];     // gated (A-layout)
  __shared__ int s_wid[4];
  __shared__ int s_hidx[64];                   // pair p = nb*4 + row

  const int tid = threadIdx.x;
  const int w = tid >> 6, ln = tid & 63, q = ln >> 4, m = ln & 15;
  const int col  = w * 16 + m;                 // this wave-lane's output col
  const int base = t * N_ + blockIdx.x * 4;    // first message row

  if (tid < 4) s_wid[tid] = word_ids[base + tid];
  if (tid < 64){
    const int row = tid & 3, nb = tid >> 2;
    s_hidx[tid] = (nb < NB_) ? h_nei[(base + row) * NB_ + nb] : E_;
  }
  __syncthreads();

  // stage 64 pair-rows (512B coalesced each)
  #pragma unroll
  for (int it = 0; it < 2; ++it){
    const int task = it * 1024 + tid;
    const int row = task >> 5, ch = task & 31;
    *(uix4*)(&hn[row*264 + ch*8]) =
        *(const uix4*)(hb16 + (size_t)s_hidx[row]*256 + ch*8);
  }
  __syncthreads();

  // xr C-init from table (D row 4q+i == msg i; bias folded)
  f32x4 xr;
  #pragma unroll
  for (int i = 0; i < 4; ++i) xr[i] = xrtab[(size_t)s_wid[i] * 256 + col];

  // persistent Ur B-frags for this wave's 16 cols (8 uix4 = 32 VGPR)
  uix4 Bur[8];
  {
    const u16* bp = Ur16 + (size_t)col * 256 + q * 8;
    #pragma unroll
    for (int kb = 0; kb < 8; ++kb) Bur[kb] = *(const uix4*)(bp + kb*32);
  }

  // r-gate GEMM over 4 pair-tiles (Bur register-resident)
  float ga[4] = {0.f,0.f,0.f,0.f}, su[4] = {0.f,0.f,0.f,0.f};
  #pragma unroll
  for (int j = 0; j < 4; ++j){
    uix4 Ah[8];
    #pragma unroll
    for (int kb = 0; kb < 8; ++kb)
      Ah[kb] = *(const uix4*)(&hn[(j*16 + m)*264 + kb*32 + q*8]);
    f32x4 a = xr;
    #pragma unroll
    for (int kb = 0; kb < 8; ++kb) a = mfma16(Ah[kb], Bur[kb], a);
    #pragma unroll
    for (int i = 0; i < 4; ++i){
      const float hv = b2f(hn[(j*16 + 4*q + i)*264 + col]);
      ga[i] += sig_(a[i]) * hv;
      su[i] += hv;
    }
  }

  // reduce over nb partition (quads): nb = 4j+q -> sum over q
  #pragma unroll
  for (int i = 0; i < 4; ++i){
    ga[i] += __shfl_xor(ga[i], 16, 64);
    ga[i] += __shfl_xor(ga[i], 32, 64);
    su[i] += __shfl_xor(su[i], 16, 64);
    su[i] += __shfl_xor(su[i], 32, 64);
  }
  if (q == 0){
    #pragma unroll
    for (int i = 0; i < 4; ++i){
      sh[i][col] = f2b(su[i]);
      gl[i][col] = f2b(ga[i]);
    }
  }
  __syncthreads();

  // z / h~ GEMMs (K=256, C-init from tables), combine, store
  f32x4 az, ah;
  #pragma unroll
  for (int i = 0; i < 4; ++i){
    az[i] = xztab[(size_t)s_wid[i] * 256 + col];
    ah[i] = xhtab[(size_t)s_wid[i] * 256 + col];
  }
  {
    uix4 As[8];
    #pragma unroll
    for (int kb = 0; kb < 8; ++kb) As[kb] = *(const uix4*)(&sh[m & 3][kb*32 + q*8]);
    const u16* bz = Wz16 + (size_t)col * 512 + 256 + q * 8;  // sum_h half
    #pragma unroll
    for (int kb = 0; kb < 8; ++kb) az = mfma16(As[kb], *(const uix4*)(bz + kb*32), az);
  }
  {
    uix4 Ag[8];
    #pragma unroll
    for (int kb = 0; kb < 8; ++kb) Ag[kb] = *(const uix4*)(&gl[m & 3][kb*32 + q*8]);
    const u16* bh = Wh16 + (size_t)col * 512 + 256 + q * 8;  // gated half
    #pragma unroll
    for (int kb = 0; kb < 8; ++kb) ah = mfma16(Ag[kb], *(const uix4*)(bh + kb*32), ah);
  }
  if (q == 0){
    #pragma unroll
    for (int i = 0; i < 4; ++i){
      const float z  = sig_(az[i]);
      const float ht = tanhf(ah[i]);
      const float nh = (1.f - z) * su[i] + z * ht;
      hb16[(size_t)(base + i) * 256 + col] = f2b(nh);
    }
  }
}

// ---- merged heads ----------------------------------------------------------
struct PredSm {
  u16   hd[4][16][264];
  int   tgt[64];
  float mask[64];
  float nll[64], hit[64], msk[64];
};
struct StopSm {
  u16   so[64][264];
  int   oidx[64][NB_];
  int   wid[64], ctx[64];
  float tgt[64];
  float b0[64], b1[64];
};
constexpr size_t SMU_ = sizeof(StopSm) > sizeof(PredSm) ? sizeof(StopSm)
                                                        : sizeof(PredSm);

__device__ void pred_body(int bid, char* smraw,
    const u16* __restrict__ hb16, const u16* __restrict__ Ww16,
    const float* __restrict__ Wb, const u16* __restrict__ Wo16,
    const float* __restrict__ Wob, const u16* __restrict__ xt16,
    const int* __restrict__ contexts, const int* __restrict__ pred_targets,
    const int* __restrict__ direction, const int* __restrict__ root_word_ids,
    float* __restrict__ accum)
{
  PredSm& sm = *(PredSm*)smraw;
  const int tid = threadIdx.x;
  const int p0  = bid * 64;
  const int w = tid >> 6, ln = tid & 63, q = ln >> 4, m = ln & 15;
  const int r0 = w * 16;

  if (tid < 64){
    const int p = p0 + tid;
    int tg; float mk;
    if (p < B_){ tg = root_word_ids[p]; mk = 1.f; }
    else { tg = pred_targets[p - B_]; mk = (float)direction[p - B_]; }
    sm.tgt[tid] = tg; sm.mask[tid] = mk;
  }
  const int p    = p0 + r0 + m;
  const int hrow = (p < B_) ? E_ : (p - B_);
  const int ctx  = (p < B_) ? p  : contexts[p - B_];
  __syncthreads();

  // GEMM1: hid = relu([h | xtree] @ Ww^T + Wb)   (K = 384)
  uix4 A1[12];
  {
    const u16* hp = hb16 + (size_t)hrow * 256 + q * 8;
    #pragma unroll
    for (int j = 0; j < 8; ++j) A1[j] = *(const uix4*)(hp + j * 32);
    const u16* xp = xt16 + (size_t)ctx * 128 + q * 8;
    #pragma unroll
    for (int j = 0; j < 4; ++j) A1[8 + j] = *(const uix4*)(xp + j * 32);
  }
  for (int t = 0; t < 16; ++t){
    f32x4 acc = {0.f, 0.f, 0.f, 0.f};
    const u16* bp = Ww16 + (size_t)(t*16 + m) * 384 + q * 8;
    #pragma unroll
    for (int j = 0; j < 12; ++j) acc = mfma16(A1[j], *(const uix4*)(bp + j*32), acc);
    const float bias = Wb[t*16 + m];
    #pragma unroll
    for (int i = 0; i < 4; ++i)
      sm.hd[w][q*4 + i][t*16 + m] = f2b(fmaxf(acc[i] + bias, 0.f));
  }
  __syncthreads();

  // GEMM2: scores = hid @ Wo^T + Wob, online softmax, B-prefetch
  uix4 A2[8];
  #pragma unroll
  for (int j = 0; j < 8; ++j) A2[j] = *(const uix4*)(&sm.hd[w][m][j*32 + q*8]);

  int tgtc[4];
  #pragma unroll
  for (int i = 0; i < 4; ++i) tgtc[i] = sm.tgt[r0 + q*4 + i];
  float mrun[4], lrun[4], amax[4], tval[4]; int aidx[4];
  #pragma unroll
  for (int i = 0; i < 4; ++i){
    mrun[i] = -1e30f; lrun[i] = 0.f; amax[i] = -1e30f; tval[i] = -1e30f; aidx[i] = 0;
  }

  uix4 Bf[8];
  {
    const u16* bp = Wo16 + (size_t)m * 256 + q * 8;
    #pragma unroll
    for (int j = 0; j < 8; ++j) Bf[j] = *(const uix4*)(bp + j*32);
  }
  for (int t = 0; t < 50; ++t){
    uix4 Bn[8];
    if (t < 49){
      const u16* bp = Wo16 + (size_t)((t+1)*16 + m) * 256 + q * 8;
      #pragma unroll
      for (int j = 0; j < 8; ++j) Bn[j] = *(const uix4*)(bp + j*32);
    } else {
      #pragma unroll
      for (int j = 0; j < 8; ++j) Bn[j] = Bf[j];
    }
    f32x4 acc = {0.f, 0.f, 0.f, 0.f};
    #pragma unroll
    for (int j = 0; j < 8; ++j) acc = mfma16(A2[j], Bf[j], acc);
    const int c = t*16 + m;
    const float bias = Wob[c];
    #pragma unroll
    for (int i = 0; i < 4; ++i){
      const float v = acc[i] + bias;
      if (c == tgtc[i]) tval[i] = v;
      if (v > amax[i]){ amax[i] = v; aidx[i] = c; }
      const float nm = fmaxf(mrun[i], v);
      lrun[i] = lrun[i] * __expf(mrun[i] - nm) + __expf(v - nm);
      mrun[i] = nm;
    }
    #pragma unroll
    for (int j = 0; j < 8; ++j) Bf[j] = Bn[j];
  }
  #pragma unroll
  for (int msk = 1; msk < 16; msk <<= 1){
    #pragma unroll
    for (int i = 0; i < 4; ++i){
      const float om = __shfl_xor(mrun[i], msk, 64);
      const float ol = __shfl_xor(lrun[i], msk, 64);
      const float nm = fmaxf(mrun[i], om);
      lrun[i] = lrun[i] * __expf(mrun[i] - nm) + ol * __expf(om - nm);
      mrun[i] = nm;
      const float oa = __shfl_xor(amax[i], msk, 64);
      const int   oi = __shfl_xor(aidx[i], msk, 64);
      if (oa > amax[i] || (oa == amax[i] && oi < aidx[i])){ amax[i] = oa; aidx[i] = oi; }
      tval[i] = fmaxf(tval[i], __shfl_xor(tval[i], msk, 64));
    }
  }
  if (m == 0){
    #pragma unroll
    for (int i = 0; i < 4; ++i){
      const int r = r0 + q*4 + i;
      const float mk  = sm.mask[r];
      const float nll = mrun[i] + __logf(lrun[i]) - tval[i];
      sm.nll[r] = nll * mk;
      sm.hit[r] = (aidx[i] == tgtc[i]) ? mk : 0.f;
      sm.msk[r] = mk;
    }
  }
  __syncthreads();
  if (tid < 64){
    float a = sm.nll[tid], b = sm.hit[tid], c2 = sm.msk[tid];
    #pragma unroll
    for (int off = 32; off > 0; off >>= 1){
      a += __shfl_down(a, off, 64); b += __shfl_down(b, off, 64); c2 += __shfl_down(c2, off, 64);
    }
    if (tid == 0){
      atomicAdd(&accum[0], a); atomicAdd(&accum[1], b); atomicAdd(&accum[2], c2);
    }
  }
}

__device__ void stop_body(int bid, char* smraw,
    const u16* __restrict__ hb16, const u16* __restrict__ emb16,
    const u16* __restrict__ Ui16, const float* __restrict__ Uib,
    const u16* __restrict__ Uw16, const float* __restrict__ Ub,
    const float* __restrict__ Uo, const float* __restrict__ Uob,
    const u16* __restrict__ xt16,
    const int* __restrict__ word_ids, const int* __restrict__ o_nei,
    const int* __restrict__ contexts, const int* __restrict__ direction,
    const int* __restrict__ root_word_ids, const int* __restrict__ root_o_idx,
    float* __restrict__ accum)
{
  StopSm& sm = *(StopSm*)smraw;
  const int tid = threadIdx.x;
  const int p0  = bid * 64;
  const int w = tid >> 6, ln = tid & 63, q = ln >> 4, m = ln & 15;
  const int r0 = w * 16;

  if (tid < 64){
    const int s = p0 + tid;
    if (s < E_){ sm.wid[tid] = word_ids[s]; sm.ctx[tid] = contexts[s];
                 sm.tgt[tid] = (float)direction[s]; }
    else { const int b = s - E_; sm.wid[tid] = root_word_ids[b]; sm.ctx[tid] = b;
           sm.tgt[tid] = 0.f; }
  }
  for (int k = tid; k < 64 * NB_; k += 256){
    const int r = k / NB_, nb = k % NB_;
    const int s = p0 + r;
    sm.oidx[r][nb] = (s < E_) ? o_nei[(size_t)s * NB_ + nb]
                              : root_o_idx[(size_t)(s - E_) * NB_ + nb];
  }
  __syncthreads();

  // stage sum_o: task-parallel (row, 16-col slice), coalesced uix4 gathers
  for (int it = 0; it < 4; ++it){
    const int task = it * 256 + tid;
    const int row = task >> 4, sl = task & 15;
    float a[16];
    #pragma unroll
    for (int c = 0; c < 16; ++c) a[c] = 0.f;
    #pragma unroll
    for (int nb = 0; nb < NB_; ++nb){
      const u16* p = hb16 + (size_t)sm.oidx[row][nb] * 256 + sl * 16;
      const uix4 v0 = *(const uix4*)(p);
      const uix4 v1 = *(const uix4*)(p + 8);
      #pragma unroll
      for (int c = 0; c < 4; ++c){
        a[2*c]     += b2f((u16)(v0[c] & 0xffffu));
        a[2*c + 1] += b2f((u16)(v0[c] >> 16));
        a[8 + 2*c] += b2f((u16)(v1[c] & 0xffffu));
        a[9 + 2*c] += b2f((u16)(v1[c] >> 16));
      }
    }
    uix4 o0, o1;
    #pragma unroll
    for (int c = 0; c < 4; ++c){
      o0[c] = (unsigned)f2b(a[2*c])   | ((unsigned)f2b(a[2*c+1]) << 16);
      o1[c] = (unsigned)f2b(a[8+2*c]) | ((unsigned)f2b(a[9+2*c]) << 16);
    }
    *(uix4*)(&sm.so[row][sl*16])     = o0;
    *(uix4*)(&sm.so[row][sl*16 + 8]) = o1;
  }
  __syncthreads();

  // A for GEMM1: [emb | sum_o]  (K = 512)
  uix4 A1[16];
  {
    const u16* ep = emb16 + (size_t)sm.wid[r0 + m] * 256 + q * 8;
    #pragma unroll
    for (int j = 0; j < 8; ++j) A1[j] = *(const uix4*)(ep + j * 32);
    #pragma unroll
    for (int j = 0; j < 8; ++j) A1[8 + j] = *(const uix4*)(&sm.so[r0 + m][j*32 + q*8]);
  }
  __syncthreads();   // all waves captured so -> safe to overwrite with h1

  // GEMM1: h1 = relu(inp @ Ui^T + Uib) -> so region (wave-private rows)
  for (int t = 0; t < 16; ++t){
    f32x4 acc = {0.f, 0.f, 0.f, 0.f};
    const u16* bp = Ui16 + (size_t)(t*16 + m) * 512 + q * 8;
    #pragma unroll
    for (int j = 0; j < 16; ++j) acc = mfma16(A1[j], *(const uix4*)(bp + j*32), acc);
    const float bias = Uib[t*16 + m];
    #pragma unroll
    for (int i = 0; i < 4; ++i)
      sm.so[r0 + q*4 + i][t*16 + m] = f2b(fmaxf(acc[i] + bias, 0.f));
  }
  __syncthreads();

  // GEMM2: h2 = relu([h1 | xtree] @ Uw^T + Ub); s = h2 . Uo + Uob
  uix4 A2[12];
  {
    #pragma unroll
    for (int j = 0; j < 8; ++j) A2[j] = *(const uix4*)(&sm.so[r0 + m][j*32 + q*8]);
    const u16* xp = xt16 + (size_t)sm.ctx[r0 + m] * 128 + q * 8;
    #pragma unroll
    for (int j = 0; j < 4; ++j) A2[8 + j] = *(const uix4*)(xp + j * 32);
  }
  float sp[4] = {0.f, 0.f, 0.f, 0.f};
  uix4 Bf[12];
  {
    const u16* bp = Uw16 + (size_t)m * 384 + q * 8;
    #pragma unroll
    for (int j = 0; j < 12; ++j) Bf[j] = *(const uix4*)(bp + j*32);
  }
  for (int t = 0; t < 16; ++t){
    uix4 Bn[12];
    if (t < 15){
      const u16* bp = Uw16 + (size_t)((t+1)*16 + m) * 384 + q * 8;
      #pragma unroll
      for (int j = 0; j < 12; ++j) Bn[j] = *(const uix4*)(bp + j*32);
    } else {
      #pragma unroll
      for (int j = 0; j < 12; ++j) Bn[j] = Bf[j];
    }
    f32x4 acc = {0.f, 0.f, 0.f, 0.f};
    #pragma unroll
    for (int j = 0; j < 12; ++j) acc = mfma16(A2[j], Bf[j], acc);
    const int c = t*16 + m;
    const float bias = Ub[c];
    const float uo   = Uo[c];
    #pragma unroll
    for (int i = 0; i < 4; ++i) sp[i] += fmaxf(acc[i] + bias, 0.f) * uo;
    #pragma unroll
    for (int j = 0; j < 12; ++j) Bf[j] = Bn[j];
  }
  #pragma unroll
  for (int msk = 1; msk < 16; msk <<= 1){
    #pragma unroll
    for (int i = 0; i < 4; ++i) sp[i] += __shfl_xor(sp[i], msk, 64);
  }
  if (m == 0){
    const float ub = Uob[0];
    #pragma unroll
    for (int i = 0; i < 4; ++i){
      const int r = r0 + q*4 + i;
      const float s   = sp[i] + ub;
      const float tgt = sm.tgt[r];
      sm.b0[r] = fmaxf(s, 0.f) - s * tgt + log1pf(__expf(-fabsf(s)));
      const float pb = (s >= 0.f) ? 1.f : 0.f;
      sm.b1[r] = (pb == tgt) ? 1.f : 0.f;
    }
  }
  __syncthreads();
  if (tid < 64){
    float a = sm.b0[tid], b = sm.b1[tid];
    #pragma unroll
    for (int off = 32; off > 0; off >>= 1){
      a += __shfl_down(a, off, 64); b += __shfl_down(b, off, 64);
    }
    if (tid == 0){ atomicAdd(&accum[3], a); atomicAdd(&accum[4], b); }
  }
}

__global__ __launch_bounds__(256) void k_heads(
    const u16* __restrict__ hb16, const u16* __restrict__ emb16,
    const u16* __restrict__ Ww16, const float* __restrict__ Wb,
    const u16* __restrict__ Wo16, const float* __restrict__ Wob,
    const u16* __restrict__ Ui16, const float* __restrict__ Uib,
    const u16* __restrict__ Uw16, const float* __restrict__ Ub,
    const float* __restrict__ Uo, const float* __restrict__ Uob,
    const u16* __restrict__ xt16,
    const int* __restrict__ word_ids, const int* __restrict__ o_nei,
    const int* __restrict__ contexts, const int* __restrict__ pred_targets,
    const int* __restrict__ direction, const int* __restrict__ root_word_ids,
    const int* __restrict__ root_o_idx, float* __restrict__ accum)
{
  __shared__ __align__(16) char smraw[SMU_];
  const int b = blockIdx.x;
  if (b < PREDB_){
    pred_body(b, smraw, hb16, Ww16, Wb, Wo16, Wob, xt16,
              contexts, pred_targets, direction, root_word_ids, accum);
  } else {
    stop_body(b - PREDB_, smraw, hb16, emb16, Ui16, Uib, Uw16, Ub, Uo, Uob,
              xt16, word_ids, o_nei, contexts, direction,
              root_word_ids, root_o_idx, accum);
  }
}

// ---- finalize --------------------------------------------------------------
__global__ void k_final(const float* __restrict__ acc, float* __restrict__ out){
  if (threadIdx.x == 0 && blockIdx.x == 0){
    out[0] = acc[0] / (float)B_;               // pred_loss
    out[1] = acc[3] / (float)B_;               // stop_loss
    out[2] = acc[1] / acc[2];                  // pred_acc
    out[3] = acc[4] / (float)(E_ + B_);        // stop_acc
  }
}

} // anonymous namespace

extern "C" void kernel_launch(void* const* d_in, const int* in_sizes, int n_in,
                              void* d_out, int out_size, void* d_ws, size_t ws_size,
                              hipStream_t stream)
{
  const float* emb   = (const float*)d_in[0];
  const float* Wz    = (const float*)d_in[1];
  const float* Wzb   = (const float*)d_in[2];
  const float* Wr    = (const float*)d_in[3];
  const float* Wrb   = (const float*)d_in[4];
  const float* Ur    = (const float*)d_in[5];
  const float* Wh    = (const float*)d_in[6];
  const float* Whb   = (const float*)d_in[7];
  const float* Ww    = (const float*)d_in[8];
  const float* Wb    = (const float*)d_in[9];
  const float* Wo    = (const float*)d_in[10];
  const float* Wob   = (const float*)d_in[11];
  const float* Uw    = (const float*)d_in[12];
  const float* Ub    = (const float*)d_in[13];
  const float* Ui    = (const float*)d_in[14];
  const float* Uib   = (const float*)d_in[15];
  const float* Uo    = (const float*)d_in[16];
  const float* Uob   = (const float*)d_in[17];
  const float* xtree = (const float*)d_in[18];
  const int* word_ids      = (const int*)d_in[19];
  const int* h_nei_idx     = (const int*)d_in[20];
  const int* o_nei_idx     = (const int*)d_in[21];
  const int* contexts      = (const int*)d_in[22];
  const int* pred_targets  = (const int*)d_in[23];
  const int* direction     = (const int*)d_in[24];
  const int* root_word_ids = (const int*)d_in[25];
  const int* root_o_idx    = (const int*)d_in[26];

  char*  wsb   = (char*)d_ws;
  float* accum = (float*)wsb;
  size_t off = 256;
  u16* hb16  = (u16*)(wsb + off); off += (size_t)(E_ + 1) * H_ * 2;  // 16.78 MB
  u16* emb16 = (u16*)(wsb + off); off += 204800u * 2;
  u16* xt16  = (u16*)(wsb + off); off += 32768u * 2;
  u16* Ww16  = (u16*)(wsb + off); off += 98304u * 2;
  u16* Wo16  = (u16*)(wsb + off); off += 204800u * 2;
  u16* Ui16  = (u16*)(wsb + off); off += 131072u * 2;
  u16* Uw16  = (u16*)(wsb + off); off += 98304u * 2;
  u16* Wz16  = (u16*)(wsb + off); off += 131072u * 2;
  u16* Wr16  = (u16*)(wsb + off); off += 65536u * 2;
  u16* Ur16  = (u16*)(wsb + off); off += 65536u * 2;
  u16* Wh16  = (u16*)(wsb + off); off += 131072u * 2;
  float* xrtab = (float*)(wsb + off); off += 204800u * 4;
  float* xztab = (float*)(wsb + off); off += 204800u * 4;
  float* xhtab = (float*)(wsb + off); off += 204800u * 4;
  float* out = (float*)d_out;

  hipLaunchKernelGGL(k_cvt, dim3(4544), dim3(256), 0, stream,
                     emb, xtree, Ww, Wo, Ui, Uw, Wz, Wr, Ur, Wh,
                     emb16, xt16, Ww16, Wo16, Ui16, Uw16,
                     Wz16, Wr16, Ur16, Wh16);
  hipLaunchKernelGGL(k_init, dim3(1), dim3(256), 0, stream, accum, hb16);
  hipLaunchKernelGGL(k_tab, dim3(50), dim3(256), 0, stream,
                     emb16, Wr16, Wrb, Wz16, Wzb, Wh16, Whb,
                     xrtab, xztab, xhtab);

  for (int t = 0; t < T_; ++t){
    hipLaunchKernelGGL(k_gru, dim3(N_ / 4), dim3(1024), 0, stream,
                       Wz16, Ur16, Wh16, xrtab, xztab, xhtab,
                       word_ids, h_nei_idx, hb16, t);
  }

  hipLaunchKernelGGL(k_heads, dim3(PREDB_ + STOPB_), dim3(256), 0, stream,
                     hb16, emb16, Ww16, Wb, Wo16, Wob, Ui16, Uib, Uw16, Ub,
                     Uo, Uob, xt16, word_ids, o_nei_idx, contexts,
                     pred_targets, direction, root_word_ids, root_o_idx,
                     accum);

  hipLaunchKernelGGL(k_final, dim3(1), dim3(1), 0, stream, accum, out);
}